// Round 6
// baseline (176.937 us; speedup 1.0000x reference)
//
#include <hip/hip_runtime.h>

#define N_IMG   1024
#define N_VIEWS 90
#define CENTER  512
#define TILE    64
#define NYB     (N_IMG / TILE)      // 16 y-blocks
#define MAXH    92                  // bbox rows <= 63*sqrt(2)+2 slack
#define MAXS    129
#define NTHREADS 512
#define NWAVES   8

// x_in =  ca*X + sa*Y + cx,  cx = CENTER*(1 - ca - sa)
// y_in = -sa*X + ca*Y + cy,  cy = CENTER*(1 - ca + sa)
// Fixed fmaf chain: corner extremes == sample extremes (monotone per variable),
// so the bbox from the 4 corners bounds every sample's floor exactly.
__device__ __forceinline__ void map_coords(float ca, float sa, float cx, float cy,
                                           float Xf, float Yf,
                                           float& x_in, float& y_in) {
    const float fx0 = fmaf(ca, Xf, cx);
    const float fy0 = fmaf(-sa, Xf, cy);
    x_in = fmaf(sa, Yf, fx0);
    y_in = fmaf(ca, Yf, fy0);
}

// STRIDE=127 (theta<90):  127 mod 32 = -1 -> bank ~ x - y, lane step |ca+sa| in [1,1.414]
// STRIDE=129 (theta>=90): 129 mod 32 = +1 -> bank ~ x + y, lane step |ca-sa| in [1,1.414]
// Row footprint is 96 px (one 24-lane float4 write) <= STRIDE, no cross-row clobber.
template<int STRIDE>
__device__ __forceinline__ float tile_work(const float* __restrict__ img,
                                           float* __restrict__ tile,
                                           int lane, int wv,
                                           int iy0, int h, int base4,
                                           float sa, float ca, float fx0, float fy0,
                                           int Ybase, bool interior) {
    // ---- stage: 2 rows per wave-iter; 24 lanes x float4 = 96 px per row ----
    {
        const int lrow = lane / 24;          // 0,1 active; 2 -> idle (lanes 48..63)
        const int lcol = (lane - lrow * 24) * 4;
        if (lrow < 2) {
            for (int r = 2 * wv; r < h; r += 2 * NWAVES) {
                const int rr = r + lrow;
                if (rr < h) {
                    const float4 v = *(const float4*)(img + (size_t)(iy0 + rr) * N_IMG + base4 + lcol);
                    *(float4*)(tile + rr * STRIDE + lcol) = v;   // ds_write_b128
                }
            }
        }
    }
    __syncthreads();

    float acc = 0.0f;
    const float basef = -(float)(iy0 * STRIDE + base4);
    const float Sf = (float)STRIDE;

    if (interior) {
        #pragma unroll
        for (int i = 0; i < TILE / NWAVES; ++i) {
            const float Yf   = (float)(Ybase + i);
            const float x_in = fmaf(sa, Yf, fx0);
            const float y_in = fmaf(ca, Yf, fy0);
            const float x0f = floorf(x_in);
            const float y0f = floorf(y_in);
            const float wx  = x_in - x0f;
            const float wy  = y_in - y0f;
            // y0f*S + x0f <= 1023*129+1023 < 2^23 -> exact in fp32
            const int li = (int)(fmaf(y0f, Sf, x0f) + basef);
            const float t00 = tile[li];
            const float t01 = tile[li + 1];
            const float t10 = tile[li + STRIDE];
            const float t11 = tile[li + STRIDE + 1];
            const float top = fmaf(wx, t01 - t00, t00);
            const float bot = fmaf(wx, t11 - t10, t10);
            acc += fmaf(wy, bot - top, top);
        }
    } else {
        #pragma unroll
        for (int i = 0; i < TILE / NWAVES; ++i) {
            const float Yf   = (float)(Ybase + i);
            const float x_in = fmaf(sa, Yf, fx0);
            const float y_in = fmaf(ca, Yf, fy0);
            const float x0f = floorf(x_in);
            const float y0f = floorf(y_in);
            const float wx  = x_in - x0f;
            const float wy  = y_in - y0f;
            const int x0 = (int)x0f;
            const int y0 = (int)y0f;
            const int x0c = min(max(x0,     0), N_IMG - 1);
            const int x1c = min(max(x0 + 1, 0), N_IMG - 1);
            const int y0c = min(max(y0,     0), N_IMG - 1);
            const int y1c = min(max(y0 + 1, 0), N_IMG - 1);
            const float wxa = (x0     >= 0 && x0     < N_IMG) ? (1.0f - wx) : 0.0f;
            const float wxb = (x0 + 1 >= 0 && x0 + 1 < N_IMG) ? wx          : 0.0f;
            const float wya = (y0     >= 0 && y0     < N_IMG) ? (1.0f - wy) : 0.0f;
            const float wyb = (y0 + 1 >= 0 && y0 + 1 < N_IMG) ? wy          : 0.0f;
            const int r0 = (y0c - iy0) * STRIDE - base4;
            const int r1 = (y1c - iy0) * STRIDE - base4;
            const float t00 = tile[r0 + x0c];
            const float t01 = tile[r0 + x1c];
            const float t10 = tile[r1 + x0c];
            const float t11 = tile[r1 + x1c];
            acc += wya * fmaf(wxa, t00, wxb * t01)
                 + wyb * fmaf(wxa, t10, wxb * t11);
        }
    }
    return acc;
}

__global__ __launch_bounds__(NTHREADS) void radon_tile(const float* __restrict__ img,
                                                       const float* __restrict__ theta,
                                                       float* __restrict__ partial,
                                                       float* __restrict__ out,
                                                       int mode) {
    __shared__ float tile[MAXH * MAXS];   // 47.5 KB -> 3 blocks/CU, 24 waves

    const int a  = blockIdx.z;
    const int X0 = blockIdx.x * TILE;
    const int Y0 = blockIdx.y * TILE;
    const int tid  = threadIdx.x;
    const int lane = tid & 63;
    const int wv   = tid >> 6;            // 0..7

    float* __restrict__ pslot = partial + ((size_t)(a * NYB + blockIdx.y) << 10) + X0;

    const float ang = theta[a] * 0.017453292519943295f;
    float sa, ca;
    __sincosf(ang, &sa, &ca);
    const float cx = (float)CENTER * (1.0f - ca - sa);
    const float cy = (float)CENTER * (1.0f - ca + sa);

    // ---- bbox from the 4 tile corners ----
    float x00, y00, x01, y01, x10, y10, x11, y11;
    map_coords(ca, sa, cx, cy, (float)X0,        (float)Y0,        x00, y00);
    map_coords(ca, sa, cx, cy, (float)(X0 + 63), (float)Y0,        x01, y01);
    map_coords(ca, sa, cx, cy, (float)X0,        (float)(Y0 + 63), x10, y10);
    map_coords(ca, sa, cx, cy, (float)(X0 + 63), (float)(Y0 + 63), x11, y11);
    const float xmin = fminf(fminf(x00, x01), fminf(x10, x11));
    const float xmax = fmaxf(fmaxf(x00, x01), fmaxf(x10, x11));
    const float ymin = fminf(fminf(y00, y01), fminf(y10, y11));
    const float ymax = fmaxf(fmaxf(y00, y01), fmaxf(y10, y11));

    const int ix0_raw = (int)floorf(xmin);
    const int ix1_raw = (int)floorf(xmax) + 1;
    const int iy0_raw = (int)floorf(ymin);
    const int iy1_raw = (int)floorf(ymax) + 1;

    const int ix0 = max(0, ix0_raw);
    const int ix1 = min(N_IMG - 1, ix1_raw);
    const int iy0 = max(0, iy0_raw);
    const int iy1 = min(N_IMG - 1, iy1_raw);

    if (ix1 < ix0 || iy1 < iy0) {          // tile maps fully outside image
        if (mode == 0) { if (tid < 64) pslot[tid] = 0.0f; }
        return;                             // mode 1: out pre-zeroed
    }

    // 96-px staging window: 16B-aligned, fully in-image, covers [ix0..ix1]
    // (ix1 - (ix0 & ~3) <= 92 + 3 = 95 < 96).
    const int base4 = min(ix0 & ~3, N_IMG - 96);
    const int h     = iy1 - iy0 + 1;        // <= 92

    const int X = X0 + lane;
    const float Xf  = (float)X;
    const float fx0 = fmaf(ca, Xf, cx);
    const float fy0 = fmaf(-sa, Xf, cy);
    const int Ybase = Y0 + wv * (TILE / NWAVES);

    const bool interior = (ix0_raw >= 0) && (ix1_raw <= N_IMG - 1) &&
                          (iy0_raw >= 0) && (iy1_raw <= N_IMG - 1);

    // Block-uniform branch: theta<90 (ca>0) -> stride 127; else stride 129.
    float acc;
    if (ca > 0.0f)
        acc = tile_work<127>(img, tile, lane, wv, iy0, h, base4,
                             sa, ca, fx0, fy0, Ybase, interior);
    else
        acc = tile_work<129>(img, tile, lane, wv, iy0, h, base4,
                             sa, ca, fx0, fy0, Ybase, interior);

    // ---- block reduce, overlaying tile; plain store (mode 0) or atomic ----
    __syncthreads();                        // all waves done reading tile
    tile[wv * 64 + lane] = acc;
    __syncthreads();
    if (wv == 0) {
        float s = 0.0f;
        #pragma unroll
        for (int w = 0; w < NWAVES; ++w) s += tile[w * 64 + lane];
        if (mode == 0) pslot[lane] = s;
        else           atomicAdd(&out[X * N_VIEWS + a], s);
    }
}

__global__ __launch_bounds__(256) void reduce_partials(const float* __restrict__ partial,
                                                       float* __restrict__ out) {
    const int g = blockIdx.x * 256 + threadIdx.x;   // [0, 90*1024)
    const int a = g >> 10;
    const int X = g & 1023;
    float s = 0.0f;
    #pragma unroll
    for (int yb = 0; yb < NYB; ++yb)
        s += partial[((size_t)(a * NYB + yb) << 10) + X];
    out[X * N_VIEWS + a] = s;
}

extern "C" void kernel_launch(void* const* d_in, const int* in_sizes, int n_in,
                              void* d_out, int out_size, void* d_ws, size_t ws_size,
                              hipStream_t stream) {
    const float* img   = (const float*)d_in[0];   // [1024, 1024] f32
    const float* theta = (const float*)d_in[1];   // [90] f32 degrees
    float* out     = (float*)d_out;               // [1024, 90] f32
    float* partial = (float*)d_ws;                // [90][16][1024] f32 partials

    const size_t needed = (size_t)N_VIEWS * NYB * N_IMG * sizeof(float);  // 5.9 MB
    const int mode = (ws_size >= needed) ? 0 : 1;
    if (mode == 1)
        hipMemsetAsync(d_out, 0, (size_t)out_size * sizeof(float), stream);

    dim3 grid(N_IMG / TILE, N_IMG / TILE, N_VIEWS);   // 16 x 16 x 90, one dispatch
    radon_tile<<<grid, NTHREADS, 0, stream>>>(img, theta, partial, out, mode);

    if (mode == 0)
        reduce_partials<<<(N_VIEWS * N_IMG) / 256, 256, 0, stream>>>(partial, out);
}

// Round 7
// 146.264 us; speedup vs baseline: 1.2097x; 1.2097x over previous
//
#include <hip/hip_runtime.h>

#define N_IMG   1024
#define N_VIEWS 90
#define CENTER  512
#define TILE    64
#define NYB     (N_IMG / TILE)      // 16 y-blocks
#define MAXH    92                  // bbox rows <= 63*sqrt(2)+2 slack
#define NTHREADS 512
#define NWAVES   8
#define TILE_WORDS 9088             // max(92*97=8924, 92*96+256 DMA-overshoot pad)

// x_in =  ca*X + sa*Y + cx,  cx = CENTER*(1 - ca - sa)
// y_in = -sa*X + ca*Y + cy,  cy = CENTER*(1 - ca + sa)
// Fixed fmaf chain: corner extremes == sample extremes (monotone per variable),
// so the bbox from the 4 corners bounds every sample's floor exactly.
__device__ __forceinline__ void map_coords(float ca, float sa, float cx, float cy,
                                           float Xf, float Yf,
                                           float& x_in, float& y_in) {
    const float fx0 = fmaf(ca, Xf, cx);
    const float fy0 = fmaf(-sa, Xf, cy);
    x_in = fmaf(sa, Yf, fx0);
    y_in = fmaf(ca, Yf, fy0);
}

// Async global->LDS DMA. 4B: lane i -> l + i*4. 16B: lane i -> l + i*16.
// LDS base must be wave-uniform; global ptr is per-lane. No waits issued here;
// __syncthreads() drains vmcnt.
__device__ __forceinline__ void gload_lds4(const float* g, float* l) {
    __builtin_amdgcn_global_load_lds((const __attribute__((address_space(1))) void*)g,
                                     (__attribute__((address_space(3))) void*)l,
                                     4, 0, 0);
}
__device__ __forceinline__ void gload_lds16(const float* g, float* l) {
    __builtin_amdgcn_global_load_lds((const __attribute__((address_space(1))) void*)g,
                                     (__attribute__((address_space(3))) void*)l,
                                     16, 0, 0);
}

// ---------------- Steep path (45 <= theta <= 135): R5 structure ----------------
// STRIDE=95 (ca>0):  95 mod 32 = -1 -> bank ~ x - y, lane step |ca+sa| in [1,1.414]
// STRIDE=97 (ca<=0): 97 mod 32 = +1 -> bank ~ x + y, lane step |ca-sa| in [1,1.414]
template<int STRIDE>
__device__ __forceinline__ float tile_steep(const float* __restrict__ img,
                                            float* __restrict__ tile,
                                            int lane, int wv,
                                            int iy0, int h, int ix0, int ix1,
                                            float sa, float ca, float fx0, float fy0,
                                            int Ybase, bool interior) {
    // two full-wave 64-dword column segments (always in-image, no masking)
    const int a0x = min(ix0, N_IMG - 64);
    const int b0x = max(a0x, ix1 - 63);
    const int dB  = b0x - a0x;              // 0..28 -> used width <= 92 < STRIDE
    {
        const float* g = img + (size_t)(iy0 + wv) * N_IMG + a0x + lane;
        float* l = tile + wv * STRIDE;
        for (int r = wv; r < h; r += NWAVES) {
            gload_lds4(g, l);
            if (dB > 0) gload_lds4(g + dB, l + dB);
            g += NWAVES * N_IMG;
            l += NWAVES * STRIDE;
        }
    }
    __syncthreads();

    float acc = 0.0f;
    const float basef = -(float)(iy0 * STRIDE + a0x);
    const float Sf = (float)STRIDE;

    if (interior) {
        #pragma unroll
        for (int i = 0; i < TILE / NWAVES; ++i) {
            const float Yf   = (float)(Ybase + i);
            const float x_in = fmaf(sa, Yf, fx0);
            const float y_in = fmaf(ca, Yf, fy0);
            const float x0f = floorf(x_in);
            const float y0f = floorf(y_in);
            const float wx  = x_in - x0f;
            const float wy  = y_in - y0f;
            const int li = (int)(fmaf(y0f, Sf, x0f) + basef);  // exact in fp32
            const float t00 = tile[li];
            const float t01 = tile[li + 1];
            const float t10 = tile[li + STRIDE];
            const float t11 = tile[li + STRIDE + 1];
            const float top = fmaf(wx, t01 - t00, t00);
            const float bot = fmaf(wx, t11 - t10, t10);
            acc += fmaf(wy, bot - top, top);
        }
    } else {
        #pragma unroll
        for (int i = 0; i < TILE / NWAVES; ++i) {
            const float Yf   = (float)(Ybase + i);
            const float x_in = fmaf(sa, Yf, fx0);
            const float y_in = fmaf(ca, Yf, fy0);
            const float x0f = floorf(x_in);
            const float y0f = floorf(y_in);
            const float wx  = x_in - x0f;
            const float wy  = y_in - y0f;
            const int x0 = (int)x0f;
            const int y0 = (int)y0f;
            const int x0c = min(max(x0,     0), N_IMG - 1);
            const int x1c = min(max(x0 + 1, 0), N_IMG - 1);
            const int y0c = min(max(y0,     0), N_IMG - 1);
            const int y1c = min(max(y0 + 1, 0), N_IMG - 1);
            const float wxa = (x0     >= 0 && x0     < N_IMG) ? (1.0f - wx) : 0.0f;
            const float wxb = (x0 + 1 >= 0 && x0 + 1 < N_IMG) ? wx          : 0.0f;
            const float wya = (y0     >= 0 && y0     < N_IMG) ? (1.0f - wy) : 0.0f;
            const float wyb = (y0 + 1 >= 0 && y0 + 1 < N_IMG) ? wy          : 0.0f;
            const int r0 = (y0c - iy0) * STRIDE - a0x;
            const int r1 = (y1c - iy0) * STRIDE - a0x;
            const float t00 = tile[r0 + x0c];
            const float t01 = tile[r0 + x1c];
            const float t10 = tile[r1 + x0c];
            const float t11 = tile[r1 + x1c];
            acc += wya * fmaf(wxa, t00, wxb * t01)
                 + wyb * fmaf(wxa, t10, wxb * t11);
        }
    }
    return acc;
}

// ------------- Shallow path (theta<45 or >135): wide async DMA, stride 96 -------------
// Bank = addr mod 32 = (x - base4) mod 32 (96*y == 0 mod 32); per-lane x step
// |ca| >= 0.707 keeps banks spread. Staging: contiguous h*96-dword tile via
// global_load_lds dwordx4 — 1 KB per wave-instr, all async.
__device__ __forceinline__ float tile_shallow(const float* __restrict__ img,
                                              float* __restrict__ tile,
                                              int lane, int wv,
                                              int iy0, int h, int base4,
                                              float sa, float ca, float fx0, float fy0,
                                              int Ybase, bool interior) {
    {
        const int D = h * 96;                         // <= 8832 dwords
        for (int o = wv * 256; o < D; o += NWAVES * 256) {
            const int d = o + 4 * lane;               // dword index in tile
            const int r = (unsigned)d / 96u;          // row (overshoot lanes: r<=94)
            const int c = d - r * 96;                 // 0..92, 4-aligned -> 16B aligned
            const int gr = min(iy0 + r, N_IMG - 1);   // keep overshoot reads in-image
            const float* g = img + (size_t)gr * N_IMG + base4 + c;  // per-lane
            gload_lds16(g, tile + o);                 // wave-uniform LDS base
        }
    }
    __syncthreads();

    float acc = 0.0f;
    const float basef = -(float)(iy0 * 96 + base4);

    if (interior) {
        #pragma unroll
        for (int i = 0; i < TILE / NWAVES; ++i) {
            const float Yf   = (float)(Ybase + i);
            const float x_in = fmaf(sa, Yf, fx0);
            const float y_in = fmaf(ca, Yf, fy0);
            const float x0f = floorf(x_in);
            const float y0f = floorf(y_in);
            const float wx  = x_in - x0f;
            const float wy  = y_in - y0f;
            const int li = (int)(fmaf(y0f, 96.0f, x0f) + basef);  // exact in fp32
            const float t00 = tile[li];
            const float t01 = tile[li + 1];
            const float t10 = tile[li + 96];
            const float t11 = tile[li + 97];
            const float top = fmaf(wx, t01 - t00, t00);
            const float bot = fmaf(wx, t11 - t10, t10);
            acc += fmaf(wy, bot - top, top);
        }
    } else {
        #pragma unroll
        for (int i = 0; i < TILE / NWAVES; ++i) {
            const float Yf   = (float)(Ybase + i);
            const float x_in = fmaf(sa, Yf, fx0);
            const float y_in = fmaf(ca, Yf, fy0);
            const float x0f = floorf(x_in);
            const float y0f = floorf(y_in);
            const float wx  = x_in - x0f;
            const float wy  = y_in - y0f;
            const int x0 = (int)x0f;
            const int y0 = (int)y0f;
            const int x0c = min(max(x0,     0), N_IMG - 1);
            const int x1c = min(max(x0 + 1, 0), N_IMG - 1);
            const int y0c = min(max(y0,     0), N_IMG - 1);
            const int y1c = min(max(y0 + 1, 0), N_IMG - 1);
            const float wxa = (x0     >= 0 && x0     < N_IMG) ? (1.0f - wx) : 0.0f;
            const float wxb = (x0 + 1 >= 0 && x0 + 1 < N_IMG) ? wx          : 0.0f;
            const float wya = (y0     >= 0 && y0     < N_IMG) ? (1.0f - wy) : 0.0f;
            const float wyb = (y0 + 1 >= 0 && y0 + 1 < N_IMG) ? wy          : 0.0f;
            const int r0 = (y0c - iy0) * 96 - base4;
            const int r1 = (y1c - iy0) * 96 - base4;
            const float t00 = tile[r0 + x0c];
            const float t01 = tile[r0 + x1c];
            const float t10 = tile[r1 + x0c];
            const float t11 = tile[r1 + x1c];
            acc += wya * fmaf(wxa, t00, wxb * t01)
                 + wyb * fmaf(wxa, t10, wxb * t11);
        }
    }
    return acc;
}

__global__ __launch_bounds__(NTHREADS) void radon_tile(const float* __restrict__ img,
                                                       const float* __restrict__ theta,
                                                       float* __restrict__ partial,
                                                       float* __restrict__ out,
                                                       int mode) {
    __shared__ float tile[TILE_WORDS];   // 36.4 KB -> 4 blocks/CU, 32 waves

    const int a  = blockIdx.z;
    const int X0 = blockIdx.x * TILE;
    const int Y0 = blockIdx.y * TILE;
    const int tid  = threadIdx.x;
    const int lane = tid & 63;
    const int wv   = tid >> 6;            // 0..7

    float* __restrict__ pslot = partial + ((size_t)(a * NYB + blockIdx.y) << 10) + X0;

    const float ang = theta[a] * 0.017453292519943295f;
    float sa, ca;
    __sincosf(ang, &sa, &ca);
    const float cx = (float)CENTER * (1.0f - ca - sa);
    const float cy = (float)CENTER * (1.0f - ca + sa);

    // ---- bbox from the 4 tile corners ----
    float x00, y00, x01, y01, x10, y10, x11, y11;
    map_coords(ca, sa, cx, cy, (float)X0,        (float)Y0,        x00, y00);
    map_coords(ca, sa, cx, cy, (float)(X0 + 63), (float)Y0,        x01, y01);
    map_coords(ca, sa, cx, cy, (float)X0,        (float)(Y0 + 63), x10, y10);
    map_coords(ca, sa, cx, cy, (float)(X0 + 63), (float)(Y0 + 63), x11, y11);
    const float xmin = fminf(fminf(x00, x01), fminf(x10, x11));
    const float xmax = fmaxf(fmaxf(x00, x01), fmaxf(x10, x11));
    const float ymin = fminf(fminf(y00, y01), fminf(y10, y11));
    const float ymax = fmaxf(fmaxf(y00, y01), fmaxf(y10, y11));

    const int ix0_raw = (int)floorf(xmin);
    const int ix1_raw = (int)floorf(xmax) + 1;
    const int iy0_raw = (int)floorf(ymin);
    const int iy1_raw = (int)floorf(ymax) + 1;

    const int ix0 = max(0, ix0_raw);
    const int ix1 = min(N_IMG - 1, ix1_raw);
    const int iy0 = max(0, iy0_raw);
    const int iy1 = min(N_IMG - 1, iy1_raw);

    if (ix1 < ix0 || iy1 < iy0) {          // tile maps fully outside image
        if (mode == 0) { if (tid < 64) pslot[tid] = 0.0f; }
        return;                             // mode 1: out pre-zeroed
    }

    const int h = iy1 - iy0 + 1;            // <= 92

    const int X = X0 + lane;
    const float Xf  = (float)X;
    const float fx0 = fmaf(ca, Xf, cx);
    const float fy0 = fmaf(-sa, Xf, cy);
    const int Ybase = Y0 + wv * (TILE / NWAVES);

    const bool interior = (ix0_raw >= 0) && (ix1_raw <= N_IMG - 1) &&
                          (iy0_raw >= 0) && (iy1_raw <= N_IMG - 1);

    // Block-uniform 3-way split on angle class.
    float acc;
    if (fabsf(ca) > 0.7072f) {
        // 96-px 16B-aligned window covering [ix0..ix1] (ix1 - (ix0&~3) <= 95)
        const int base4 = min(ix0 & ~3, N_IMG - 96);
        acc = tile_shallow(img, tile, lane, wv, iy0, h, base4,
                           sa, ca, fx0, fy0, Ybase, interior);
    } else if (ca > 0.0f) {
        acc = tile_steep<95>(img, tile, lane, wv, iy0, h, ix0, ix1,
                             sa, ca, fx0, fy0, Ybase, interior);
    } else {
        acc = tile_steep<97>(img, tile, lane, wv, iy0, h, ix0, ix1,
                             sa, ca, fx0, fy0, Ybase, interior);
    }

    // ---- block reduce, overlaying tile; plain store (mode 0) or atomic ----
    __syncthreads();                        // all waves done reading tile
    tile[wv * 64 + lane] = acc;
    __syncthreads();
    if (wv == 0) {
        float s = 0.0f;
        #pragma unroll
        for (int w = 0; w < NWAVES; ++w) s += tile[w * 64 + lane];
        if (mode == 0) pslot[lane] = s;
        else           atomicAdd(&out[X * N_VIEWS + a], s);
    }
}

__global__ __launch_bounds__(256) void reduce_partials(const float* __restrict__ partial,
                                                       float* __restrict__ out) {
    const int g = blockIdx.x * 256 + threadIdx.x;   // [0, 90*1024)
    const int a = g >> 10;
    const int X = g & 1023;
    float s = 0.0f;
    #pragma unroll
    for (int yb = 0; yb < NYB; ++yb)
        s += partial[((size_t)(a * NYB + yb) << 10) + X];
    out[X * N_VIEWS + a] = s;
}

extern "C" void kernel_launch(void* const* d_in, const int* in_sizes, int n_in,
                              void* d_out, int out_size, void* d_ws, size_t ws_size,
                              hipStream_t stream) {
    const float* img   = (const float*)d_in[0];   // [1024, 1024] f32
    const float* theta = (const float*)d_in[1];   // [90] f32 degrees
    float* out     = (float*)d_out;               // [1024, 90] f32
    float* partial = (float*)d_ws;                // [90][16][1024] f32 partials

    const size_t needed = (size_t)N_VIEWS * NYB * N_IMG * sizeof(float);  // 5.9 MB
    const int mode = (ws_size >= needed) ? 0 : 1;
    if (mode == 1)
        hipMemsetAsync(d_out, 0, (size_t)out_size * sizeof(float), stream);

    dim3 grid(N_IMG / TILE, N_IMG / TILE, N_VIEWS);   // 16 x 16 x 90, one dispatch
    radon_tile<<<grid, NTHREADS, 0, stream>>>(img, theta, partial, out, mode);

    if (mode == 0)
        reduce_partials<<<(N_VIEWS * N_IMG) / 256, 256, 0, stream>>>(partial, out);
}

// Round 8
// 144.370 us; speedup vs baseline: 1.2256x; 1.0131x over previous
//
#include <hip/hip_runtime.h>

#define N_IMG   1024
#define N_VIEWS 90
#define CENTER  512
#define TILE    64
#define NYB     (N_IMG / TILE)      // 16 y-blocks
#define NTHREADS 512
#define NWAVES   8
#define YPT      (TILE / NWAVES)    // 8 samples per thread
#define TILE_WORDS 9216             // 92*97=8924 used + drift-overshoot pad; 36.9 KB

// x_in =  ca*X + sa*Y + cx,  cx = CENTER*(1 - ca - sa)
// y_in = -sa*X + ca*Y + cy,  cy = CENTER*(1 - ca + sa)
// Fixed fmaf chain: corner extremes == sample extremes (monotone per variable),
// so the bbox from the 4 corners bounds every sample's floor exactly.
__device__ __forceinline__ void map_coords(float ca, float sa, float cx, float cy,
                                           float Xf, float Yf,
                                           float& x_in, float& y_in) {
    const float fx0 = fmaf(ca, Xf, cx);
    const float fy0 = fmaf(-sa, Xf, cy);
    x_in = fmaf(sa, Yf, fx0);
    y_in = fmaf(ca, Yf, fy0);
}

// Async global->LDS DMA. 4B: lane i -> l + i*4. 16B: lane i -> l + i*16.
// LDS base wave-uniform; global ptr per-lane. __syncthreads() drains vmcnt.
__device__ __forceinline__ void gload_lds4(const float* g, float* l) {
    __builtin_amdgcn_global_load_lds((const __attribute__((address_space(1))) void*)g,
                                     (__attribute__((address_space(3))) void*)l,
                                     4, 0, 0);
}
__device__ __forceinline__ void gload_lds16(const float* g, float* l) {
    __builtin_amdgcn_global_load_lds((const __attribute__((address_space(1))) void*)g,
                                     (__attribute__((address_space(3))) void*)l,
                                     16, 0, 0);
}

// Unified bilinear sampler. Staged window maps image (y,x) -> tile[(y-iy0)*STRIDE
// + (x-win)]; basef = -(iy0*STRIDE + win) precomputed in float (exact, < 2^23).
// Incremental coords: <=7 sequential adds from exact fmaf base; drift <=2e-4 px,
// tile[] padded so a +-1 floor overshoot (weight ~0) stays in-bounds.
template<int STRIDE>
__device__ __forceinline__ float sample_tile(const float* __restrict__ tile,
                                             float sa, float ca,
                                             float x_in, float y_in,
                                             float basef, int iy0, int win,
                                             bool interior) {
    float acc = 0.0f;
    const float Sf = (float)STRIDE;
    if (interior) {
        #pragma unroll
        for (int i = 0; i < YPT; ++i) {
            const float x0f = floorf(x_in);
            const float y0f = floorf(y_in);
            const float wx  = x_in - x0f;
            const float wy  = y_in - y0f;
            const int li = (int)(fmaf(y0f, Sf, x0f) + basef);   // exact in fp32
            const float t00 = tile[li];
            const float t01 = tile[li + 1];
            const float t10 = tile[li + STRIDE];
            const float t11 = tile[li + STRIDE + 1];
            const float top = fmaf(wx, t01 - t00, t00);
            const float bot = fmaf(wx, t11 - t10, t10);
            acc += fmaf(wy, bot - top, top);
            x_in += sa; y_in += ca;
        }
    } else {
        #pragma unroll
        for (int i = 0; i < YPT; ++i) {
            const float x0f = floorf(x_in);
            const float y0f = floorf(y_in);
            const float wx  = x_in - x0f;
            const float wy  = y_in - y0f;
            const int x0 = (int)x0f;
            const int y0 = (int)y0f;
            const int x0c = min(max(x0,     0), N_IMG - 1);
            const int x1c = min(max(x0 + 1, 0), N_IMG - 1);
            const int y0c = min(max(y0,     0), N_IMG - 1);
            const int y1c = min(max(y0 + 1, 0), N_IMG - 1);
            const float wxa = (x0     >= 0 && x0     < N_IMG) ? (1.0f - wx) : 0.0f;
            const float wxb = (x0 + 1 >= 0 && x0 + 1 < N_IMG) ? wx          : 0.0f;
            const float wya = (y0     >= 0 && y0     < N_IMG) ? (1.0f - wy) : 0.0f;
            const float wyb = (y0 + 1 >= 0 && y0 + 1 < N_IMG) ? wy          : 0.0f;
            const int r0 = (y0c - iy0) * STRIDE - win;
            const int r1 = (y1c - iy0) * STRIDE - win;
            const float t00 = tile[r0 + x0c];
            const float t01 = tile[r0 + x1c];
            const float t10 = tile[r1 + x0c];
            const float t11 = tile[r1 + x1c];
            acc += wya * fmaf(wxa, t00, wxb * t01)
                 + wyb * fmaf(wxa, t10, wxb * t11);
            x_in += sa; y_in += ca;
        }
    }
    return acc;
}

__global__ __launch_bounds__(NTHREADS) void radon_tile(const float* __restrict__ img,
                                                       const float* __restrict__ theta,
                                                       float* __restrict__ partial,
                                                       float* __restrict__ out,
                                                       int mode) {
    __shared__ float tile[TILE_WORDS];   // 36.9 KB -> 4 blocks/CU, 32 waves
    __shared__ float fpar[4];            // sa, ca, cx, cy
    __shared__ int   ipar[7];            // iy0, h, win, dB, path, interior, empty

    const int a  = blockIdx.z;
    const int X0 = blockIdx.x * TILE;
    const int Y0 = blockIdx.y * TILE;
    const int tid  = threadIdx.x;
    const int lane = tid & 63;
    const int wv   = tid >> 6;            // 0..7

    // ---- wave 0 computes all block-uniform params once; others wait ----
    if (wv == 0) {
        const float ang = theta[a] * 0.017453292519943295f;
        float sa, ca;
        __sincosf(ang, &sa, &ca);
        const float cx = (float)CENTER * (1.0f - ca - sa);
        const float cy = (float)CENTER * (1.0f - ca + sa);

        float x00, y00, x01, y01, x10, y10, x11, y11;
        map_coords(ca, sa, cx, cy, (float)X0,        (float)Y0,        x00, y00);
        map_coords(ca, sa, cx, cy, (float)(X0 + 63), (float)Y0,        x01, y01);
        map_coords(ca, sa, cx, cy, (float)X0,        (float)(Y0 + 63), x10, y10);
        map_coords(ca, sa, cx, cy, (float)(X0 + 63), (float)(Y0 + 63), x11, y11);
        const float xmin = fminf(fminf(x00, x01), fminf(x10, x11));
        const float xmax = fmaxf(fmaxf(x00, x01), fmaxf(x10, x11));
        const float ymin = fminf(fminf(y00, y01), fminf(y10, y11));
        const float ymax = fmaxf(fmaxf(y00, y01), fmaxf(y10, y11));

        const int ix0_raw = (int)floorf(xmin);
        const int ix1_raw = (int)floorf(xmax) + 1;
        const int iy0_raw = (int)floorf(ymin);
        const int iy1_raw = (int)floorf(ymax) + 1;

        const int ix0 = max(0, ix0_raw);
        const int ix1 = min(N_IMG - 1, ix1_raw);
        const int iy0 = max(0, iy0_raw);
        const int iy1 = min(N_IMG - 1, iy1_raw);

        int path, win, dB = 0;
        if (fabsf(ca) > 0.7072f) {                 // shallow: wide DMA, stride 96
            path = 0; win = min(ix0 & ~3, N_IMG - 96);
        } else {                                   // steep: dual 64-px segments
            path = (ca > 0.0f) ? 1 : 2;
            win = min(ix0, N_IMG - 64);
            dB  = max(win, ix1 - 63) - win;        // 0..28
        }
        if (tid == 0) {
            fpar[0] = sa; fpar[1] = ca; fpar[2] = cx; fpar[3] = cy;
            ipar[0] = iy0; ipar[1] = iy1 - iy0 + 1; ipar[2] = win; ipar[3] = dB;
            ipar[4] = path;
            ipar[5] = (ix0_raw >= 0) && (ix1_raw <= N_IMG - 1) &&
                      (iy0_raw >= 0) && (iy1_raw <= N_IMG - 1);
            ipar[6] = (ix1 < ix0) || (iy1 < iy0);
        }
    }
    __syncthreads();

    float* __restrict__ pslot = partial + ((size_t)(a * NYB + blockIdx.y) << 10) + X0;

    if (ipar[6]) {                          // tile maps fully outside image
        if (mode == 0 && tid < 64) pslot[tid] = 0.0f;
        return;                             // mode 1: out pre-zeroed
    }

    const float sa = fpar[0], ca = fpar[1], cx = fpar[2], cy = fpar[3];
    const int iy0 = ipar[0], h = ipar[1], win = ipar[2], dB = ipar[3];
    const int path = ipar[4];
    const bool interior = ipar[5];

    // ---- per-lane sample-line setup ----
    const int X = X0 + lane;
    const float Xf  = (float)X;
    const float fx0 = fmaf(ca, Xf, cx);
    const float fy0 = fmaf(-sa, Xf, cy);
    const float Ybf = (float)(Y0 + wv * YPT);
    const float x_in = fmaf(sa, Ybf, fx0);
    const float y_in = fmaf(ca, Ybf, fy0);

    float acc;
    if (path == 0) {
        // stage contiguous h*96 tile via 16B async DMA (1 KB/wave-instr)
        const int D = h * 96;
        for (int o = wv * 256; o < D; o += NWAVES * 256) {
            const int d = o + 4 * lane;
            const int r = (unsigned)d / 96u;           // overshoot lanes clamp below
            const int c = d - r * 96;
            const int gr = min(iy0 + r, N_IMG - 1);
            gload_lds16(img + (size_t)gr * N_IMG + win + c, tile + o);
        }
        __syncthreads();
        acc = sample_tile<96>(tile, sa, ca, x_in, y_in,
                              -(float)(iy0 * 96 + win), iy0, win, interior);
    } else {
        // stage via dual 64-px 4B async DMA, odd stride for conflict-free reads
        const int STRIDE = (path == 1) ? 95 : 97;
        {
            const float* g = img + (size_t)(iy0 + wv) * N_IMG + win + lane;
            float* l = tile + wv * STRIDE;
            for (int r = wv; r < h; r += NWAVES) {
                gload_lds4(g, l);
                if (dB > 0) gload_lds4(g + dB, l + dB);
                g += NWAVES * N_IMG;
                l += NWAVES * STRIDE;
            }
        }
        __syncthreads();
        if (path == 1)
            acc = sample_tile<95>(tile, sa, ca, x_in, y_in,
                                  -(float)(iy0 * 95 + win), iy0, win, interior);
        else
            acc = sample_tile<97>(tile, sa, ca, x_in, y_in,
                                  -(float)(iy0 * 97 + win), iy0, win, interior);
    }

    // ---- block reduce, overlaying tile; plain store (mode 0) or atomic ----
    __syncthreads();                        // all waves done reading tile
    tile[wv * 64 + lane] = acc;
    __syncthreads();
    if (wv == 0) {
        float s = 0.0f;
        #pragma unroll
        for (int w = 0; w < NWAVES; ++w) s += tile[w * 64 + lane];
        if (mode == 0) pslot[lane] = s;
        else           atomicAdd(&out[X * N_VIEWS + a], s);
    }
}

__global__ __launch_bounds__(256) void reduce_partials(const float* __restrict__ partial,
                                                       float* __restrict__ out) {
    const int g = blockIdx.x * 256 + threadIdx.x;   // [0, 90*1024)
    const int a = g >> 10;
    const int X = g & 1023;
    float s = 0.0f;
    #pragma unroll
    for (int yb = 0; yb < NYB; ++yb)
        s += partial[((size_t)(a * NYB + yb) << 10) + X];
    out[X * N_VIEWS + a] = s;
}

extern "C" void kernel_launch(void* const* d_in, const int* in_sizes, int n_in,
                              void* d_out, int out_size, void* d_ws, size_t ws_size,
                              hipStream_t stream) {
    const float* img   = (const float*)d_in[0];   // [1024, 1024] f32
    const float* theta = (const float*)d_in[1];   // [90] f32 degrees
    float* out     = (float*)d_out;               // [1024, 90] f32
    float* partial = (float*)d_ws;                // [90][16][1024] f32 partials

    const size_t needed = (size_t)N_VIEWS * NYB * N_IMG * sizeof(float);  // 5.9 MB
    const int mode = (ws_size >= needed) ? 0 : 1;
    if (mode == 1)
        hipMemsetAsync(d_out, 0, (size_t)out_size * sizeof(float), stream);

    dim3 grid(N_IMG / TILE, N_IMG / TILE, N_VIEWS);   // 16 x 16 x 90, one dispatch
    radon_tile<<<grid, NTHREADS, 0, stream>>>(img, theta, partial, out, mode);

    if (mode == 0)
        reduce_partials<<<(N_VIEWS * N_IMG) / 256, 256, 0, stream>>>(partial, out);
}